// Round 7
// baseline (204.928 us; speedup 1.0000x reference)
//
#include <hip/hip_runtime.h>
#include <cstdint>
#include <cstddef>

// DenseGAT, N=4096, IN_DIM=256, H=4, D=64, NEG_SLOPE=0.2
// w[i,j,h] = eb * max(t5, tt);  tt = ui*uj = exp(.2(ei+ej)),
//   t5 = ui5*uj5 = exp(ei+ej) = tt^5 (exact), eb = exp(bias) or 0 (masked).
// R7: ALL hot loops barrier-free. Attn loads bias directly into MFMA
// A-fragment layout per lane (no LDS, no __syncthreads in K-loop).
// Wh GEMM via f16 MFMA with hi/lo precision split (fp32-quality Wh).

typedef _Float16 f16x4 __attribute__((ext_vector_type(4)));
typedef _Float16 f16x8 __attribute__((ext_vector_type(8)));
typedef float f32x4 __attribute__((ext_vector_type(4)));

#define NN 4096
#define CH 4

// ---- Kernel 0: transpose + hi/lo split W -> Wt_hi/Wt_lo (f16) ------------
// grid 16 (4 k-tiles x 4 c-tiles), block 256.
__global__ __launch_bounds__(256) void wtprep(const float* __restrict__ W,
                                              _Float16* __restrict__ Wth,
                                              _Float16* __restrict__ Wtl) {
  __shared__ float s[64][65];
  const int t = threadIdx.x;
  const int kt = blockIdx.x >> 2, ct = blockIdx.x & 3;
  {
    const int r = t >> 2, cq = (t & 3) * 16;
    #pragma unroll
    for (int q = 0; q < 4; q++) {
      float4 v = *(const float4*)&W[(size_t)(kt * 64 + r) * 256 + ct * 64 + cq + q * 4];
      s[r][cq + q * 4 + 0] = v.x; s[r][cq + q * 4 + 1] = v.y;
      s[r][cq + q * 4 + 2] = v.z; s[r][cq + q * 4 + 3] = v.w;
    }
  }
  __syncthreads();
  {
    const int c = t >> 2, kq = (t & 3) * 16;
    f16x8 hi[2], lo[2];
    #pragma unroll
    for (int g = 0; g < 2; g++)
      #pragma unroll
      for (int kk = 0; kk < 8; kk++) {
        float wv = s[kq + g * 8 + kk][c];
        _Float16 hh = (_Float16)wv;
        hi[g][kk] = hh;
        lo[g][kk] = (_Float16)((wv - (float)hh) * 2048.0f);
      }
    const size_t base = (size_t)(ct * 64 + c) * 256 + kt * 64 + kq;
    *(f16x8*)&Wth[base] = hi[0]; *(f16x8*)&Wth[base + 8] = hi[1];
    *(f16x8*)&Wtl[base] = lo[0]; *(f16x8*)&Wtl[base + 8] = lo[1];
  }
}

// ---- Kernel 1: Wh = h @ W via MFMA hi/lo split; + Vt, ui/uj exps ---------
// grid (64 row-tiles of 64, 4 heads), block 256 = 4 waves (wave = 16 rows).
// Barrier-free, LDS-free.
__global__ __launch_bounds__(256) void gemm_wh(
    const float* __restrict__ A, const _Float16* __restrict__ Wth,
    const _Float16* __restrict__ Wtl, const float* __restrict__ av,
    float* __restrict__ Wh, _Float16* __restrict__ Vt,
    _Float16* __restrict__ uit, _Float16* __restrict__ ui5t,
    _Float16* __restrict__ ujt, _Float16* __restrict__ uj5t) {
  const int tid = threadIdx.x;
  const int lane = tid & 63;
  const int w = __builtin_amdgcn_readfirstlane(tid >> 6);
  const int m = lane & 15, quad = lane >> 4;
  const int mt = blockIdx.x;
  const int head = blockIdx.y;
  const int arow = mt * 64 + w * 16 + m;

  f32x4 dhi[4], dlo[4];
  #pragma unroll
  for (int nt = 0; nt < 4; nt++)
    #pragma unroll
    for (int r = 0; r < 4; r++) { dhi[nt][r] = 0.f; dlo[nt][r] = 0.f; }

  #pragma unroll
  for (int ks = 0; ks < 8; ks++) {
    const float* ap = A + (size_t)arow * 256 + ks * 32 + quad * 8;
    float4 v0 = *(const float4*)ap;
    float4 v1 = *(const float4*)(ap + 4);
    const float vv[8] = {v0.x, v0.y, v0.z, v0.w, v1.x, v1.y, v1.z, v1.w};
    f16x8 ah, al;
    #pragma unroll
    for (int j = 0; j < 8; j++) {
      _Float16 hh = (_Float16)vv[j];
      ah[j] = hh;
      al[j] = (_Float16)((vv[j] - (float)hh) * 2048.0f);
    }
    #pragma unroll
    for (int nt = 0; nt < 4; nt++) {
      const size_t base = (size_t)(head * 64 + nt * 16 + m) * 256 + ks * 32 + quad * 8;
      f16x8 bh = *(const f16x8*)&Wth[base];
      f16x8 bl = *(const f16x8*)&Wtl[base];
      dhi[nt] = __builtin_amdgcn_mfma_f32_16x16x32_f16(ah, bh, dhi[nt], 0, 0, 0);
      dlo[nt] = __builtin_amdgcn_mfma_f32_16x16x32_f16(al, bh, dlo[nt], 0, 0, 0);
      dlo[nt] = __builtin_amdgcn_mfma_f32_16x16x32_f16(ah, bl, dlo[nt], 0, 0, 0);
    }
  }

  f32x4 C[4];
  #pragma unroll
  for (int nt = 0; nt < 4; nt++)
    #pragma unroll
    for (int r = 0; r < 4; r++) C[nt][r] = dhi[nt][r] + dlo[nt][r] * (1.0f / 2048.0f);

  // C rows = mt*64 + w*16 + quad*4 + r; cols = head*64 + nt*16 + m
  const int crow0 = mt * 64 + w * 16 + quad * 4;
  #pragma unroll
  for (int nt = 0; nt < 4; nt++) {
    #pragma unroll
    for (int r = 0; r < 4; r++)
      Wh[(size_t)(crow0 + r) * 256 + head * 64 + nt * 16 + m] = C[nt][r];
    f16x4 tv;
    #pragma unroll
    for (int r = 0; r < 4; r++) tv[r] = (_Float16)C[nt][r];
    *(f16x4*)&Vt[(size_t)(head * 64 + nt * 16 + m) * NN + crow0] = tv;
  }

  // e_i / e_j for the 16 rows of this wave
  float ai[4], aj[4];
  #pragma unroll
  for (int nt = 0; nt < 4; nt++) {
    ai[nt] = av[head * 128 + nt * 16 + m];
    aj[nt] = av[head * 128 + 64 + nt * 16 + m];
  }
  float pi[4], pj[4];
  #pragma unroll
  for (int r = 0; r < 4; r++) {
    float si = 0.f, sj = 0.f;
    #pragma unroll
    for (int nt = 0; nt < 4; nt++) {
      si = fmaf(C[nt][r], ai[nt], si);
      sj = fmaf(C[nt][r], aj[nt], sj);
    }
    #pragma unroll
    for (int msk = 1; msk <= 8; msk <<= 1) {
      si += __shfl_xor(si, msk, 64);
      sj += __shfl_xor(sj, msk, 64);
    }
    pi[r] = si; pj[r] = sj;
  }
  if (m == 0) {
    #pragma unroll
    for (int r = 0; r < 4; r++) {
      const int row = crow0 + r;
      uit [(size_t)head * NN + row] = (_Float16)__expf(0.2f * pi[r]);
      ui5t[(size_t)head * NN + row] = (_Float16)__expf(pi[r]);
      ujt [(size_t)head * NN + row] = (_Float16)__expf(0.2f * pj[r]);
      uj5t[(size_t)head * NN + row] = (_Float16)__expf(pj[r]);
    }
  }
}

// ---- Kernel 2: fused attention, barrier-free -----------------------------
// grid (256 i-tiles of 16, CH j-chunks), block 256 = 4 waves (wave = head).
// Lane loads bias straight into A-frag layout: row i0+m, cols jt+quad*8..+7.
__global__ __launch_bounds__(256, 4) void gat_attn(
    const float* __restrict__ bias, const _Float16* __restrict__ Vt,
    const _Float16* __restrict__ uit, const _Float16* __restrict__ ui5t,
    const _Float16* __restrict__ ujt, const _Float16* __restrict__ uj5t,
    float* __restrict__ P, float* __restrict__ L) {
  const int itile = blockIdx.x;
  const int chunk = blockIdx.y;
  const int tid = threadIdx.x;
  const int lane = tid & 63;
  const int head = __builtin_amdgcn_readfirstlane(tid >> 6);
  const int m = lane & 15, quad = lane >> 4;
  const int i0 = itile * 16;
  const int j0 = chunk * (NN / CH);

  f32x4 acc[5];
  #pragma unroll
  for (int dt = 0; dt < 5; dt++)
    #pragma unroll
    for (int r = 0; r < 4; r++) acc[dt][r] = 0.f;

  const _Float16 u1 = uit [(size_t)head * NN + i0 + m];
  const _Float16 u5 = ui5t[(size_t)head * NN + i0 + m];
  const f16x8 ui8 = {u1, u1, u1, u1, u1, u1, u1, u1};
  const f16x8 u58 = {u5, u5, u5, u5, u5, u5, u5, u5};
  const f16x8 kOne = {(_Float16)1.f, (_Float16)1.f, (_Float16)1.f, (_Float16)1.f,
                      (_Float16)1.f, (_Float16)1.f, (_Float16)1.f, (_Float16)1.f};

  const float*     bp0 = bias + (size_t)(i0 + m) * NN + j0 + quad * 8;
  const _Float16*  ujb = ujt  + (size_t)head * NN + j0 + quad * 8;
  const _Float16*  u5b = uj5t + (size_t)head * NN + j0 + quad * 8;
  const _Float16*  vb  = Vt   + (size_t)(head * 64 + m) * NN + j0 + quad * 8;

  #pragma unroll 2
  for (int js = 0; js < NN / CH / 32; js++) {
    const int jo = js * 32;
    float4 v0 = *(const float4*)(bp0 + jo);
    float4 v1 = *(const float4*)(bp0 + jo + 4);
    const float g[8] = {v0.x, v0.y, v0.z, v0.w, v1.x, v1.y, v1.z, v1.w};
    f16x8 eb;
    #pragma unroll
    for (int j = 0; j < 8; j++)
      eb[j] = (_Float16)((g[j] == 0.f) ? 0.f : __expf(g[j]));
    const f16x8 uj8  = *(const f16x8*)(ujb + jo);
    const f16x8 uj58 = *(const f16x8*)(u5b + jo);
    const f16x8 a0 = eb * __builtin_elementwise_max(u58 * uj58, ui8 * uj8);
    #pragma unroll
    for (int dt = 0; dt < 4; dt++) {
      const f16x8 bfr = *(const f16x8*)(vb + (size_t)(dt * 16) * NN + jo);
      acc[dt] = __builtin_amdgcn_mfma_f32_16x16x32_f16(a0, bfr, acc[dt], 0, 0, 0);
    }
    acc[4] = __builtin_amdgcn_mfma_f32_16x16x32_f16(a0, kOne, acc[4], 0, 0, 0);
  }

  const size_t lb = (size_t)(chunk * 4 + head) * NN + i0;
  if (m == 0) {
    #pragma unroll
    for (int r = 0; r < 4; r++) L[lb + quad * 4 + r] = acc[4][r];
  }
  const size_t pbase = ((size_t)(chunk * 4 + head) * NN + i0) * 64;
  #pragma unroll
  for (int dt = 0; dt < 4; dt++)
    #pragma unroll
    for (int r = 0; r < 4; r++)
      P[pbase + (size_t)(quad * 4 + r) * 64 + dt * 16 + m] = acc[dt][r];
}

// ---- Kernel 3: reduce partials, normalize, ELU ---------------------------
// grid (256 i-tiles of 16, 4 heads), block 256. P is L3-resident (16 MB).
__global__ __launch_bounds__(256) void reduce_out(
    const float* __restrict__ P, const float* __restrict__ L,
    const float* __restrict__ Wh, float* __restrict__ out) {
  const int i0 = blockIdx.x * 16;
  const int h = blockIdx.y;
  const int t = threadIdx.x;
  const int d = t & 63;
  const int g = t >> 6;
  #pragma unroll
  for (int ii = 0; ii < 4; ii++) {
    const int i = i0 + g * 4 + ii;
    float lsum = 0.f, s = 0.f;
    #pragma unroll
    for (int c = 0; c < CH; c++) {
      lsum += L[(size_t)(c * 4 + h) * NN + i];
      s += P[((size_t)(c * 4 + h) * NN + i) * 64 + d];
    }
    const float wh = Wh[(size_t)i * 256 + h * 64 + d];
    const bool fb = (lsum == 0.f);
    float o = fb ? wh : s / lsum;
    o = (o > 0.f) ? o : (__expf(o) - 1.f);
    out[(size_t)i * 256 + h * 64 + d] = o;
  }
}

extern "C" void kernel_launch(void* const* d_in, const int* in_sizes, int n_in,
                              void* d_out, int out_size, void* d_ws, size_t ws_size,
                              hipStream_t stream) {
  const float* h_in = (const float*)d_in[0];   // (4096, 256)
  const float* adj  = (const float*)d_in[1];   // (4096, 4096)
  const float* W    = (const float*)d_in[2];   // (256, 256)
  const float* a    = (const float*)d_in[3];   // (4, 128)
  float* out = (float*)d_out;
  float* ws = (float*)d_ws;

  // ws layout (floats): Wh 1M | Vt 512K | u 32K | Wth 32K | Wtl 32K | L 64K | P 4M
  float* Wh = ws;
  _Float16* Vt   = (_Float16*)(ws + 1048576);
  _Float16* uit  = (_Float16*)(ws + 1048576 + 524288);
  _Float16* ui5t = uit + 16384;
  _Float16* ujt  = ui5t + 16384;
  _Float16* uj5t = ujt + 16384;
  _Float16* Wth  = (_Float16*)(ws + 1048576 + 524288 + 32768);
  _Float16* Wtl  = Wth + 65536;
  float* Lb = ws + 1048576 + 524288 + 32768 + 65536;
  float* Pb = Lb + (size_t)CH * 4 * 4096;

  hipLaunchKernelGGL(wtprep, dim3(16), dim3(256), 0, stream, W, Wth, Wtl);
  hipLaunchKernelGGL(gemm_wh, dim3(64, 4), dim3(256), 0, stream,
                     h_in, Wth, Wtl, a, Wh, Vt, uit, ui5t, ujt, uj5t);
  hipLaunchKernelGGL(gat_attn, dim3(256, CH), dim3(256), 0, stream,
                     adj, Vt, uit, ui5t, ujt, uj5t, Pb, Lb);
  hipLaunchKernelGGL(reduce_out, dim3(256, 4), dim3(256), 0, stream,
                     Pb, Lb, Wh, out);
}